// Round 11
// baseline (598.522 us; speedup 1.0000x reference)
//
#include <hip/hip_runtime.h>
#include <hip/hip_bf16.h>
#include <math.h>

// FFTMLP: N=32768, T=2048, NF=1025, HIDDEN=128
// Math: rfft(x1)-rfft(x2) = rfft(d), d=x1-x2. feats@W1.T folds into
//   At[t][k] = sum_f W1r[k,f]*cos(2pi f t/T) - W1i[k,f]*sin(2pi f t/T)
//   h = relu(d @ At + b1);  out = h . mean_t(W2) + mean(b2)
#define T_LEN   2048
#define NFREQ   1025
#define HID     128
#define NSAMP   32768
#define NIT     64              // 2048 / 32 t-tiles

typedef __attribute__((ext_vector_type(8)))  short short8v;   // 8 bf16 (MFMA A/B frag)
typedef __attribute__((ext_vector_type(16))) float f32x16;    // MFMA C/D frag

// ws layout (bytes)
#define AKG_OFF    0
#define W2BAR_OFF  (1u<<20)
#define B2BAR_OFF  ((1u<<20)+512)
#define PW_OFF     ((1u<<20)+1024)
#define PB_OFF     ((1u<<20)+1024+8192)

// ---------------- K1/K2: w2bar = mean_t W2, b2bar = mean b2 ----------------
__global__ __launch_bounds__(128) void k_w2_partial(const float* __restrict__ W2,
                                                    const float* __restrict__ b2,
                                                    float* __restrict__ pw,
                                                    float* __restrict__ pb) {
    const int b = blockIdx.x;
    const int c = threadIdx.x;
    const int t0 = b * 128;
    float s0 = 0.f, s1 = 0.f, s2 = 0.f, s3 = 0.f;
    #pragma unroll 4
    for (int i = 0; i < 128; i += 4) {
        s0 += W2[(long)(t0 + i + 0) * HID + c];
        s1 += W2[(long)(t0 + i + 1) * HID + c];
        s2 += W2[(long)(t0 + i + 2) * HID + c];
        s3 += W2[(long)(t0 + i + 3) * HID + c];
    }
    pw[b * HID + c] = (s0 + s1) + (s2 + s3);
    float v = b2[t0 + c];
    for (int o = 32; o > 0; o >>= 1) v += __shfl_down(v, o);
    __shared__ float sred[2];
    if ((threadIdx.x & 63) == 0) sred[threadIdx.x >> 6] = v;
    __syncthreads();
    if (threadIdx.x == 0) pb[b] = sred[0] + sred[1];
}

__global__ __launch_bounds__(128) void k_w2_final(const float* __restrict__ pw,
                                                  const float* __restrict__ pb,
                                                  float* __restrict__ w2bar,
                                                  float* __restrict__ b2bar) {
    const int c = threadIdx.x;
    float s = 0.f;
    #pragma unroll
    for (int b = 0; b < 16; ++b) s += pw[b * HID + c];
    w2bar[c] = s * (1.f / (float)T_LEN);
    if (c == 0) {
        float t = 0.f;
        #pragma unroll
        for (int b = 0; b < 16; ++b) t += pb[b];
        *b2bar = t * (1.f / (float)T_LEN);
    }
}

// ---------------- KA: build Akg (At, tiled + XOR-swizzled bf16 hi/lo image) ----------------
// 256-thread blocks; one k-row of W1 in LDS (uniform-addr broadcasts, no VMEM in loop);
// f split even/odd across lane halves (chain 512); exact integer-phase resync per 128.
__global__ __launch_bounds__(256) void k_build_At(const float* __restrict__ W1,
                                                  unsigned short* __restrict__ Akg) {
    __shared__ float lW[2 * NFREQ];          // [0..1024]=Wr, [1025..2049]=Wi
    const int k  = blockIdx.x >> 4;          // 0..127
    const int tg = blockIdx.x & 15;          // 16 groups of 128 t
    const int tid = threadIdx.x;
    const float* __restrict__ Wk = W1 + (long)k * (2 * NFREQ);
    for (int i = tid; i < 2 * NFREQ; i += 256) lW[i] = Wk[i];
    __syncthreads();
    const float* __restrict__ lWr = lW;
    const float* __restrict__ lWi = lW + NFREQ;

    const int chunk = tid >> 6;
    const int fh = (tid >> 5) & 1;
    const int tl = tid & 31;
    const int t  = tg * 128 + chunk * 32 + tl;

    const float w = -6.283185307179586f / (float)T_LEN;
    float sr, cr;
    { int ph2 = (2 * t) & (T_LEN - 1); sincosf(w * (float)ph2, &sr, &cr); }
    float zr, zi;
    { int ph = (t * fh) & (T_LEN - 1); sincosf(w * (float)ph, &zi, &zr); }
    float acc = 0.f;
    int f = fh;
    for (int blk = 0; blk < 4; ++blk) {
        #pragma unroll 4
        for (int j = 0; j < 128; ++j) {
            acc = fmaf(lWr[f], zr, acc);
            acc = fmaf(lWi[f], zi, acc);
            float nzr = fmaf(zr, cr, -(zi * sr));
            float nzi = fmaf(zr, sr, zi * cr);
            zr = nzr; zi = nzi;
            f += 2;
        }
        int ph = (t * f) & (T_LEN - 1);
        sincosf(w * (float)ph, &zi, &zr);
    }
    if (fh == 0) {
        acc = fmaf(lWr[1024], zr, acc);
        acc = fmaf(lWi[1024], zi, acc);
    }
    acc += __shfl_xor(acc, 32);

    if (fh == 0) {
        __hip_bfloat16 hb = __float2bfloat16(acc);
        float hf = __bfloat162float(hb);
        __hip_bfloat16 lb = __float2bfloat16(acc - hf);
        const int tile = t >> 5, islot = (t & 31) >> 3, j = t & 7;
        const int shi = islot ^ (k & 7);
        const int slo = (islot ^ 4) ^ (k & 7);
        const long base = (long)tile * 8192 + k * 64 + j;     // ushort units
        Akg[base + shi * 8] = __builtin_bit_cast(unsigned short, hb);
        Akg[base + slo * 8] = __builtin_bit_cast(unsigned short, lb);
    }
}

// ---------------- KG: fused (x1-x2) @ At -> relu -> dot(w2bar) -> out[N] ----------------
// MFMA 32x32x16 bf16, 3-pass hi/lo. BM=128, BN=128, BK=32, 512 thr = 8 waves.
// T4 counted-vmcnt pipeline: raw s_barrier + lgkmcnt(0) only (NO __syncthreads in the
// K-loop) so the 2-tile-deep register prefetch stays in flight across barriers; the
// waits on those loads become compiler-inserted counted vmcnt(N) at the LDS-write use
// one full iteration later. 2x-unrolled loop gives static register-set names (rule 20).
__global__ __launch_bounds__(512) void k_gemm(const float* __restrict__ x1,
                                              const float* __restrict__ x2,
                                              const unsigned short* __restrict__ Akg,
                                              const float* __restrict__ b1,
                                              const float* __restrict__ w2bar,
                                              const float* __restrict__ b2bar,
                                              float* __restrict__ out) {
    __shared__ __align__(16) unsigned short ak[2][8192];   // At tile: [hid 128][8 slots][8 bf16]
    __shared__ __align__(16) unsigned short dd[2][8192];   // d tile: [row 128][8 slots][8 bf16]
    __shared__ float osum[128];

    const int tid = threadIdx.x;
    const int l   = tid & 63;
    const int w   = tid >> 6;          // 0..7
    const int wm  = w & 3;
    const int wn  = w >> 2;
    const int g   = l >> 5;
    const int m31 = l & 31;
    const long row0 = (long)blockIdx.x * 128;

    // staging assignment: thread covers row rs, t-quad j4 (8 consecutive t = 32B)
    const int rs = tid >> 2;
    const int j4 = tid & 3;
    const float* __restrict__ px1 = x1 + (row0 + rs) * T_LEN + j4 * 8;
    const float* __restrict__ px2 = x2 + (row0 + rs) * T_LEN + j4 * 8;
    const unsigned short* __restrict__ pak = Akg + tid * 16;   // 32B per thread, coalesced

    const int wr_hi = rs * 64 + ((j4 ^ (rs & 7)) * 8);         // swizzled hi-slot (ushorts)
    const int ra  = wm * 32 + m31;                             // A-frag LDS row
    const int rb0 = wn * 64 + m31;                             // B-frag LDS rows
    const int rb1 = wn * 64 + 32 + m31;

    f32x16 acc0, acc1;
    #pragma unroll
    for (int q = 0; q < 16; ++q) { acc0[q] = 0.f; acc1[q] = 0.f; }

    float4 xa0A, xa1A, xb0A, xb1A, xa0B, xa1B, xb0B, xb1B;
    uint4  ak0A, ak1A, ak0B, ak1B;

#define LOADX(S, IT) {                                                      \
        const float* p1_ = px1 + (IT) * 32;                                 \
        const float* p2_ = px2 + (IT) * 32;                                 \
        xa0##S = *(const float4*)(p1_);  xa1##S = *(const float4*)(p1_ + 4);\
        xb0##S = *(const float4*)(p2_);  xb1##S = *(const float4*)(p2_ + 4);\
        const unsigned short* pa_ = pak + (long)(IT) * 8192;                \
        ak0##S = *(const uint4*)(pa_);   ak1##S = *(const uint4*)(pa_ + 8); }

#define STAGE(S, BUF) {                                                     \
        float dv_[8] = {xa0##S.x - xb0##S.x, xa0##S.y - xb0##S.y,           \
                        xa0##S.z - xb0##S.z, xa0##S.w - xb0##S.w,           \
                        xa1##S.x - xb1##S.x, xa1##S.y - xb1##S.y,           \
                        xa1##S.z - xb1##S.z, xa1##S.w - xb1##S.w};          \
        short8v dhv_, dlv_;                                                 \
        _Pragma("unroll")                                                   \
        for (int e = 0; e < 8; ++e) {                                       \
            __hip_bfloat16 hb_ = __float2bfloat16(dv_[e]);                  \
            float lo_ = dv_[e] - __bfloat162float(hb_);                     \
            dhv_[e] = __builtin_bit_cast(short, hb_);                       \
            dlv_[e] = __builtin_bit_cast(short, __float2bfloat16(lo_));     \
        }                                                                   \
        *(short8v*)&dd[BUF][wr_hi]      = dhv_;                             \
        *(short8v*)&dd[BUF][wr_hi ^ 32] = dlv_;                             \
        *(uint4*)&ak[BUF][tid * 16]     = ak0##S;                           \
        *(uint4*)&ak[BUF][tid * 16 + 8] = ak1##S; }

#define LBAR() { asm volatile("s_waitcnt lgkmcnt(0)" ::: "memory");         \
                 __builtin_amdgcn_s_barrier();                              \
                 __builtin_amdgcn_sched_barrier(0); }

#define COMPUTE2(BUF, ACCA, ACCB) {                                         \
        _Pragma("unroll")                                                   \
        for (int kc = 0; kc < 2; ++kc) {                                    \
            const int sa_ = ((2 * kc + g) ^ (ra & 7)) * 8;                  \
            const short8v ah_ = *(const short8v*)&dd[BUF][ra * 64 + sa_];   \
            const short8v al_ = *(const short8v*)&dd[BUF][ra * 64 + (sa_ ^ 32)]; \
            const int sb0_ = ((2 * kc + g) ^ (rb0 & 7)) * 8;                \
            const short8v bh0_ = *(const short8v*)&ak[BUF][rb0 * 64 + sb0_];\
            const short8v bl0_ = *(const short8v*)&ak[BUF][rb0 * 64 + (sb0_ ^ 32)]; \
            const int sb1_ = ((2 * kc + g) ^ (rb1 & 7)) * 8;                \
            const short8v bh1_ = *(const short8v*)&ak[BUF][rb1 * 64 + sb1_];\
            const short8v bl1_ = *(const short8v*)&ak[BUF][rb1 * 64 + (sb1_ ^ 32)]; \
            ACCA = __builtin_amdgcn_mfma_f32_32x32x16_bf16(ah_, bh0_, ACCA, 0, 0, 0); \
            ACCA = __builtin_amdgcn_mfma_f32_32x32x16_bf16(ah_, bl0_, ACCA, 0, 0, 0); \
            ACCA = __builtin_amdgcn_mfma_f32_32x32x16_bf16(al_, bh0_, ACCA, 0, 0, 0); \
            ACCB = __builtin_amdgcn_mfma_f32_32x32x16_bf16(ah_, bh1_, ACCB, 0, 0, 0); \
            ACCB = __builtin_amdgcn_mfma_f32_32x32x16_bf16(ah_, bl1_, ACCB, 0, 0, 0); \
            ACCB = __builtin_amdgcn_mfma_f32_32x32x16_bf16(al_, bh1_, ACCB, 0, 0, 0); \
        } }

    // prolog: sets A (tile 0) and B (tile 1)
    LOADX(A, 0);
    LOADX(B, 1);

    for (int it2 = 0; it2 < NIT / 2; ++it2) {
        const int itA = 2 * it2;
        // ---- body A (buf 0) ----
        STAGE(A, 0);
        { int itn = itA + 2; if (itn > NIT - 1) itn = NIT - 1; LOADX(A, itn); }
        LBAR();
        COMPUTE2(0, acc0, acc1);
        // ---- body B (buf 1) ----
        STAGE(B, 1);
        { int itn = itA + 3; if (itn > NIT - 1) itn = NIT - 1; LOADX(B, itn); }
        LBAR();
        COMPUTE2(1, acc0, acc1);
    }

#undef LOADX
#undef STAGE
#undef LBAR
#undef COMPUTE2

    // epilogue: relu(acc + b1) . w2bar, reduce over n; C/D: col=l&31, row=(q&3)+8*(q>>2)+4*g
    float pres[16];
    #pragma unroll
    for (int q = 0; q < 16; ++q) pres[q] = 0.f;
    {
        const int n0 = wn * 64 + m31;
        const float bb0 = b1[n0], wb0 = w2bar[n0];
        const int n1 = wn * 64 + 32 + m31;
        const float bb1v = b1[n1], wb1 = w2bar[n1];
        #pragma unroll
        for (int q = 0; q < 16; ++q) {
            pres[q] += fmaxf(acc0[q] + bb0, 0.f) * wb0;
            pres[q] += fmaxf(acc1[q] + bb1v, 0.f) * wb1;
        }
    }
    #pragma unroll
    for (int q = 0; q < 16; ++q) {
        float s = pres[q];
        s += __shfl_xor(s, 1); s += __shfl_xor(s, 2); s += __shfl_xor(s, 4);
        s += __shfl_xor(s, 8); s += __shfl_xor(s, 16);
        pres[q] = s;
    }
    __syncthreads();
    if (wn == 0 && m31 == 0) {
        #pragma unroll
        for (int q = 0; q < 16; ++q)
            osum[wm * 32 + (q & 3) + 8 * (q >> 2) + 4 * g] = pres[q];
    }
    __syncthreads();
    if (wn == 1 && m31 == 0) {
        const float bb = *b2bar;
        #pragma unroll
        for (int q = 0; q < 16; ++q) {
            const int m = wm * 32 + (q & 3) + 8 * (q >> 2) + 4 * g;
            out[row0 + m] = pres[q] + osum[m] + bb;
        }
    }
}

extern "C" void kernel_launch(void* const* d_in, const int* in_sizes, int n_in,
                              void* d_out, int out_size, void* d_ws, size_t ws_size,
                              hipStream_t stream) {
    const float* x1 = (const float*)d_in[0];
    const float* x2 = (const float*)d_in[1];
    const float* W1 = (const float*)d_in[2];
    const float* b1 = (const float*)d_in[3];
    const float* W2 = (const float*)d_in[4];
    const float* b2 = (const float*)d_in[5];
    float* out = (float*)d_out;

    char* ws = (char*)d_ws;
    unsigned short* Akg = (unsigned short*)(ws + AKG_OFF);
    float* w2bar = (float*)(ws + W2BAR_OFF);
    float* b2bar = (float*)(ws + B2BAR_OFF);
    float* pw    = (float*)(ws + PW_OFF);
    float* pb    = (float*)(ws + PB_OFF);

    hipLaunchKernelGGL(k_w2_partial, dim3(16), dim3(128), 0, stream, W2, b2, pw, pb);
    hipLaunchKernelGGL(k_w2_final,   dim3(1),  dim3(128), 0, stream, pw, pb, w2bar, b2bar);
    hipLaunchKernelGGL(k_build_At,   dim3(2048), dim3(256), 0, stream, W1, Akg);
    hipLaunchKernelGGL(k_gemm,       dim3(NSAMP / 128), dim3(512), 0, stream,
                       x1, x2, Akg, b1, w2bar, b2bar, out);
}

// Round 12
// 586.164 us; speedup vs baseline: 1.0211x; 1.0211x over previous
//
#include <hip/hip_runtime.h>
#include <hip/hip_bf16.h>
#include <math.h>

// FFTMLP: N=32768, T=2048, NF=1025, HIDDEN=128
// Math: rfft(x1)-rfft(x2) = rfft(d), d=x1-x2. feats@W1.T folds into
//   At[t][k] = sum_f W1r[k,f]*cos(2pi f t/T) - W1i[k,f]*sin(2pi f t/T)
//   h = relu(d @ At + b1);  out = h . mean_t(W2) + mean(b2)
#define T_LEN   2048
#define NFREQ   1025
#define HID     128
#define NSAMP   32768
#define NIT     64              // 2048 / 32 t-tiles

typedef __attribute__((ext_vector_type(4)))  short short4v;   // 4 bf16 (8 B LDS write)
typedef __attribute__((ext_vector_type(8)))  short short8v;   // 8 bf16 (MFMA A/B frag)
typedef __attribute__((ext_vector_type(16))) float f32x16;    // MFMA C/D frag

// ws layout (bytes)
#define AKG_OFF    0
#define W2BAR_OFF  (1u<<20)
#define B2BAR_OFF  ((1u<<20)+512)
#define PW_OFF     ((1u<<20)+1024)
#define PB_OFF     ((1u<<20)+1024+8192)

// ---------------- K1/K2: w2bar = mean_t W2, b2bar = mean b2 ----------------
__global__ __launch_bounds__(128) void k_w2_partial(const float* __restrict__ W2,
                                                    const float* __restrict__ b2,
                                                    float* __restrict__ pw,
                                                    float* __restrict__ pb) {
    const int b = blockIdx.x;
    const int c = threadIdx.x;
    const int t0 = b * 128;
    float s0 = 0.f, s1 = 0.f, s2 = 0.f, s3 = 0.f;
    #pragma unroll 4
    for (int i = 0; i < 128; i += 4) {
        s0 += W2[(long)(t0 + i + 0) * HID + c];
        s1 += W2[(long)(t0 + i + 1) * HID + c];
        s2 += W2[(long)(t0 + i + 2) * HID + c];
        s3 += W2[(long)(t0 + i + 3) * HID + c];
    }
    pw[b * HID + c] = (s0 + s1) + (s2 + s3);
    float v = b2[t0 + c];
    for (int o = 32; o > 0; o >>= 1) v += __shfl_down(v, o);
    __shared__ float sred[2];
    if ((threadIdx.x & 63) == 0) sred[threadIdx.x >> 6] = v;
    __syncthreads();
    if (threadIdx.x == 0) pb[b] = sred[0] + sred[1];
}

__global__ __launch_bounds__(128) void k_w2_final(const float* __restrict__ pw,
                                                  const float* __restrict__ pb,
                                                  float* __restrict__ w2bar,
                                                  float* __restrict__ b2bar) {
    const int c = threadIdx.x;
    float s = 0.f;
    #pragma unroll
    for (int b = 0; b < 16; ++b) s += pw[b * HID + c];
    w2bar[c] = s * (1.f / (float)T_LEN);
    if (c == 0) {
        float t = 0.f;
        #pragma unroll
        for (int b = 0; b < 16; ++b) t += pb[b];
        *b2bar = t * (1.f / (float)T_LEN);
    }
}

// ---------------- KA: build Akg (At, tiled + XOR-swizzled bf16 hi/lo image) ----------------
// Unchanged from R9/R11 (never individually measured >185 us; do not perturb while
// k_gemm is the attributed target).
__global__ __launch_bounds__(256) void k_build_At(const float* __restrict__ W1,
                                                  unsigned short* __restrict__ Akg) {
    __shared__ float lW[2 * NFREQ];          // [0..1024]=Wr, [1025..2049]=Wi
    const int k  = blockIdx.x >> 4;          // 0..127
    const int tg = blockIdx.x & 15;          // 16 groups of 128 t
    const int tid = threadIdx.x;
    const float* __restrict__ Wk = W1 + (long)k * (2 * NFREQ);
    for (int i = tid; i < 2 * NFREQ; i += 256) lW[i] = Wk[i];
    __syncthreads();
    const float* __restrict__ lWr = lW;
    const float* __restrict__ lWi = lW + NFREQ;

    const int chunk = tid >> 6;
    const int fh = (tid >> 5) & 1;
    const int tl = tid & 31;
    const int t  = tg * 128 + chunk * 32 + tl;

    const float w = -6.283185307179586f / (float)T_LEN;
    float sr, cr;
    { int ph2 = (2 * t) & (T_LEN - 1); sincosf(w * (float)ph2, &sr, &cr); }
    float zr, zi;
    { int ph = (t * fh) & (T_LEN - 1); sincosf(w * (float)ph, &zi, &zr); }
    float acc = 0.f;
    int f = fh;
    for (int blk = 0; blk < 4; ++blk) {
        #pragma unroll 4
        for (int j = 0; j < 128; ++j) {
            acc = fmaf(lWr[f], zr, acc);
            acc = fmaf(lWi[f], zi, acc);
            float nzr = fmaf(zr, cr, -(zi * sr));
            float nzi = fmaf(zr, sr, zi * cr);
            zr = nzr; zi = nzi;
            f += 2;
        }
        int ph = (t * f) & (T_LEN - 1);
        sincosf(w * (float)ph, &zi, &zr);
    }
    if (fh == 0) {
        acc = fmaf(lWr[1024], zr, acc);
        acc = fmaf(lWi[1024], zi, acc);
    }
    acc += __shfl_xor(acc, 32);

    if (fh == 0) {
        __hip_bfloat16 hb = __float2bfloat16(acc);
        float hf = __bfloat162float(hb);
        __hip_bfloat16 lb = __float2bfloat16(acc - hf);
        const int tile = t >> 5, islot = (t & 31) >> 3, j = t & 7;
        const int shi = islot ^ (k & 7);
        const int slo = (islot ^ 4) ^ (k & 7);
        const long base = (long)tile * 8192 + k * 64 + j;     // ushort units
        Akg[base + shi * 8] = __builtin_bit_cast(unsigned short, hb);
        Akg[base + slo * 8] = __builtin_bit_cast(unsigned short, lb);
    }
}

// ---------------- KG: fused (x1-x2) @ At -> relu -> dot(w2bar) -> out[N] ----------------
// MFMA 32x32x16 bf16, 3-pass hi/lo. BM=64, BN=128, BK=32. 512 thr = 8 waves
// (4 wn x 2 wm), each wave one 32x32 output tile. grid=512 -> 2 INDEPENDENT
// blocks/CU (LDS 49 KB/block), 16 waves/CU: one block's barrier stall overlaps the
// other's compute (R11 diagnosis: 1 lockstep block/CU was the latency wall).
// T4 raw-barrier pipeline + 2-tile register prefetch retained.
__global__ __launch_bounds__(512) void k_gemm(const float* __restrict__ x1,
                                              const float* __restrict__ x2,
                                              const unsigned short* __restrict__ Akg,
                                              const float* __restrict__ b1,
                                              const float* __restrict__ w2bar,
                                              const float* __restrict__ b2bar,
                                              float* __restrict__ out) {
    __shared__ __align__(16) unsigned short ak[2][8192];   // At tile: [hid 128][8 slots][8 bf16]
    __shared__ __align__(16) unsigned short dd[2][4096];   // d tile:  [row  64][8 slots][8 bf16]
    __shared__ float osum[4][64];

    const int tid = threadIdx.x;
    const int l   = tid & 63;
    const int w   = tid >> 6;          // 0..7
    const int wn  = w & 3;             // col tile (32 hid cols)
    const int wm  = w >> 2;            // row tile (32 sample rows)
    const int g   = l >> 5;
    const int m31 = l & 31;
    const long row0 = (long)blockIdx.x * 64;

    // staging: thread -> row rs (8 thr/row), j8 = tid&7 covers t-quad j8*4..+3 (16 B)
    const int rs = tid >> 3;
    const int j8 = tid & 7;
    const float* __restrict__ px1 = x1 + (row0 + rs) * T_LEN + j8 * 4;
    const float* __restrict__ px2 = x2 + (row0 + rs) * T_LEN + j8 * 4;
    const unsigned short* __restrict__ pak = Akg + tid * 16;   // 32 B/thread, coalesced

    const int wr_hi = rs * 64 + (((j8 >> 1) ^ (rs & 7)) * 8) + (j8 & 1) * 4; // ushorts
    const int ra  = wm * 32 + m31;    // dd row (sample)
    const int rb  = wn * 32 + m31;    // ak row (hid)

    f32x16 acc;
    #pragma unroll
    for (int q = 0; q < 16; ++q) acc[q] = 0.f;

    float4 xaA, xbA, xaB, xbB;
    uint4  ak0A, ak1A, ak0B, ak1B;

#define LOADX(S, IT) {                                                      \
        xa##S = *(const float4*)(px1 + (IT) * 32);                          \
        xb##S = *(const float4*)(px2 + (IT) * 32);                          \
        const unsigned short* pa_ = pak + (long)(IT) * 8192;                \
        ak0##S = *(const uint4*)(pa_);   ak1##S = *(const uint4*)(pa_ + 8); }

#define STAGE(S, BUF) {                                                     \
        float dv_[4] = {xa##S.x - xb##S.x, xa##S.y - xb##S.y,               \
                        xa##S.z - xb##S.z, xa##S.w - xb##S.w};              \
        short4v dhv_, dlv_;                                                 \
        _Pragma("unroll")                                                   \
        for (int e = 0; e < 4; ++e) {                                       \
            __hip_bfloat16 hb_ = __float2bfloat16(dv_[e]);                  \
            float lo_ = dv_[e] - __bfloat162float(hb_);                     \
            dhv_[e] = __builtin_bit_cast(short, hb_);                       \
            dlv_[e] = __builtin_bit_cast(short, __float2bfloat16(lo_));     \
        }                                                                   \
        *(short4v*)&dd[BUF][wr_hi]      = dhv_;                             \
        *(short4v*)&dd[BUF][wr_hi ^ 32] = dlv_;                             \
        *(uint4*)&ak[BUF][tid * 16]     = ak0##S;                           \
        *(uint4*)&ak[BUF][tid * 16 + 8] = ak1##S; }

#define LBAR() { asm volatile("s_waitcnt lgkmcnt(0)" ::: "memory");         \
                 __builtin_amdgcn_s_barrier();                              \
                 __builtin_amdgcn_sched_barrier(0); }

#define COMPUTE(BUF) {                                                      \
        _Pragma("unroll")                                                   \
        for (int kc = 0; kc < 2; ++kc) {                                    \
            const int sa_ = ((2 * kc + g) ^ (ra & 7)) * 8;                  \
            const short8v ah_ = *(const short8v*)&dd[BUF][ra * 64 + sa_];   \
            const short8v al_ = *(const short8v*)&dd[BUF][ra * 64 + (sa_ ^ 32)]; \
            const int sb_ = ((2 * kc + g) ^ (rb & 7)) * 8;                  \
            const short8v bh_ = *(const short8v*)&ak[BUF][rb * 64 + sb_];   \
            const short8v bl_ = *(const short8v*)&ak[BUF][rb * 64 + (sb_ ^ 32)]; \
            acc = __builtin_amdgcn_mfma_f32_32x32x16_bf16(ah_, bh_, acc, 0, 0, 0); \
            acc = __builtin_amdgcn_mfma_f32_32x32x16_bf16(ah_, bl_, acc, 0, 0, 0); \
            acc = __builtin_amdgcn_mfma_f32_32x32x16_bf16(al_, bh_, acc, 0, 0, 0); \
        } }

    // prolog: sets A (tile 0) and B (tile 1)
    LOADX(A, 0);
    LOADX(B, 1);

    for (int it2 = 0; it2 < NIT / 2; ++it2) {
        const int itA = 2 * it2;
        // ---- body A (buf 0) ----
        STAGE(A, 0);
        { int itn = itA + 2; if (itn > NIT - 1) itn = NIT - 1; LOADX(A, itn); }
        LBAR();
        COMPUTE(0);
        // ---- body B (buf 1) ----
        STAGE(B, 1);
        { int itn = itA + 3; if (itn > NIT - 1) itn = NIT - 1; LOADX(B, itn); }
        LBAR();
        COMPUTE(1);
    }

#undef LOADX
#undef STAGE
#undef LBAR
#undef COMPUTE

    // epilogue: relu(acc + b1) . w2bar, reduce over hid cols.
    // C/D layout: col(hid) = m31, row(sample) = (q&3)+8*(q>>2)+4*g  [m74/m101]
    float pres[16];
    {
        const int n = wn * 32 + m31;
        const float bb1 = b1[n], wb = w2bar[n];
        #pragma unroll
        for (int q = 0; q < 16; ++q)
            pres[q] = fmaxf(acc[q] + bb1, 0.f) * wb;
    }
    #pragma unroll
    for (int q = 0; q < 16; ++q) {
        float s = pres[q];
        s += __shfl_xor(s, 1); s += __shfl_xor(s, 2); s += __shfl_xor(s, 4);
        s += __shfl_xor(s, 8); s += __shfl_xor(s, 16);
        pres[q] = s;
    }
    if (m31 == 0) {
        #pragma unroll
        for (int q = 0; q < 16; ++q)
            osum[wn][wm * 32 + (q & 3) + 8 * (q >> 2) + 4 * g] = pres[q];
    }
    __syncthreads();
    if (tid < 64) {
        out[row0 + tid] = osum[0][tid] + osum[1][tid] + osum[2][tid] + osum[3][tid]
                        + *b2bar;
    }
}

extern "C" void kernel_launch(void* const* d_in, const int* in_sizes, int n_in,
                              void* d_out, int out_size, void* d_ws, size_t ws_size,
                              hipStream_t stream) {
    const float* x1 = (const float*)d_in[0];
    const float* x2 = (const float*)d_in[1];
    const float* W1 = (const float*)d_in[2];
    const float* b1 = (const float*)d_in[3];
    const float* W2 = (const float*)d_in[4];
    const float* b2 = (const float*)d_in[5];
    float* out = (float*)d_out;

    char* ws = (char*)d_ws;
    unsigned short* Akg = (unsigned short*)(ws + AKG_OFF);
    float* w2bar = (float*)(ws + W2BAR_OFF);
    float* b2bar = (float*)(ws + B2BAR_OFF);
    float* pw    = (float*)(ws + PW_OFF);
    float* pb    = (float*)(ws + PB_OFF);

    hipLaunchKernelGGL(k_w2_partial, dim3(16), dim3(128), 0, stream, W2, b2, pw, pb);
    hipLaunchKernelGGL(k_w2_final,   dim3(1),  dim3(128), 0, stream, pw, pb, w2bar, b2bar);
    hipLaunchKernelGGL(k_build_At,   dim3(2048), dim3(256), 0, stream, W1, Akg);
    hipLaunchKernelGGL(k_gemm,       dim3(NSAMP / 64), dim3(512), 0, stream,
                       x1, x2, Akg, b1, w2bar, b2bar, out);
}